// Round 11
// baseline (813.681 us; speedup 1.0000x reference)
//
#include <hip/hip_runtime.h>
#include <hip/hip_fp16.h>
#include <hip/hip_cooperative_groups.h>

namespace cg = cooperative_groups;

#define EMBED 128
#define CHUNK 8             // spmm gather depth (proven R8/R10 config)
#define T_TILE 2048         // passA staging tile (LDS budget: 4 blocks/CU)
#define NB_SH 9             // 512 rows per bucket == block width
#define BCAP 16384          // per-bucket capacity (avg ~6.8K, item-buckets ~10.2K)

// inclusive Hillis-Steele scan over 512 ints in LDS
__device__ __forceinline__ void scan512(int* s, int tid) {
    #pragma unroll
    for (int off = 1; off < 512; off <<= 1) {
        int t = (tid >= off) ? s[tid - off] : 0;
        __syncthreads();
        s[tid] += t;
        __syncthreads();
    }
}

__device__ __forceinline__ void spmm_phase(const int* __restrict__ rs,
                                           const int2* __restrict__ edges,
                                           const __half* __restrict__ hin,
                                           __half* __restrict__ hout, int N) {
    const int wid    = (blockIdx.x << 3) + (threadIdx.x >> 6);
    const int lane   = threadIdx.x & 63;
    const int half   = lane >> 5;
    const int l32    = lane & 31;
    const int stride = gridDim.x << 3;    // total waves
    for (int r0 = wid * 2; r0 < N; r0 += stride * 2) {
        int row = r0 + half;
        if (row < N) {
            int s = rs[row], e = rs[row + 1];
            float4 acc = make_float4(0.f, 0.f, 0.f, 0.f);
            for (int k = s; k < e; k += CHUNK) {
                uint2 raw[CHUNK];
                float vv[CHUNK];
                #pragma unroll
                for (int j = 0; j < CHUNK; ++j) {
                    bool ok  = (k + j) < e;
                    int  idx = ok ? (k + j) : s;
                    int2 ed  = edges[idx];
                    vv[j]    = ok ? __int_as_float(ed.y) : 0.f;
                    raw[j]   = *(const uint2*)(hin + (size_t)ed.x * EMBED + 4 * l32);
                }
                #pragma unroll
                for (int j = 0; j < CHUNK; ++j) {
                    __half2 h01 = *(__half2*)&raw[j].x;
                    __half2 h23 = *(__half2*)&raw[j].y;
                    acc.x = fmaf(__half2float(h01.x), vv[j], acc.x);
                    acc.y = fmaf(__half2float(h01.y), vv[j], acc.y);
                    acc.z = fmaf(__half2float(h23.x), vv[j], acc.z);
                    acc.w = fmaf(__half2float(h23.y), vv[j], acc.w);
                }
            }
            __half2 o0 = __floats2half2_rn(acc.x, acc.y);
            __half2 o1 = __floats2half2_rn(acc.z, acc.w);
            uint2 o;
            o.x = *(unsigned int*)&o0;
            o.y = *(unsigned int*)&o1;
            *(uint2*)(hout + (size_t)row * EMBED + 4 * l32) = o;
        }
    }
}

__global__ void __launch_bounds__(512, 8)
mega(const float* __restrict__ uE, const float* __restrict__ iE,
     const int* __restrict__ L_row, const int* __restrict__ L_col,
     const float* __restrict__ L_val,
     const int* __restrict__ uIdx, const int* __restrict__ vIdx,
     float* __restrict__ out,
     __half* __restrict__ h0, __half* __restrict__ h1, __half* __restrict__ h2,
     int2* __restrict__ edges, long long* __restrict__ bedges,
     int* __restrict__ rs, int* __restrict__ bcnt,
     int N, int E, int B, int userNum, int nu8, int ntot8) {
    __shared__ long long sh_data[T_TILE];   // 16 KB
    __shared__ int sh_gpos[T_TILE];         // 8 KB
    __shared__ int sA[512], sB[512], sC[512], sD[512];  // 8 KB
    const int tid = threadIdx.x;
    const int G   = gridDim.x;
    cg::grid_group grid = cg::this_grid();
    const int NBUCK = (N + (1 << NB_SH) - 1) >> NB_SH;   // 293

    // ---------- Phase A1: fp32 -> fp16 convert (grid-stride) ----------
    for (int i = blockIdx.x * 512 + tid; i < ntot8; i += G * 512) {
        const float* src = (i < nu8) ? (uE + (size_t)i * 8)
                                     : (iE + (size_t)(i - nu8) * 8);
        float4 a = ((const float4*)src)[0];
        float4 b = ((const float4*)src)[1];
        __half2 q0 = __floats2half2_rn(a.x, a.y);
        __half2 q1 = __floats2half2_rn(a.z, a.w);
        __half2 q2 = __floats2half2_rn(b.x, b.y);
        __half2 q3 = __floats2half2_rn(b.z, b.w);
        uint4 o;
        o.x = *(unsigned int*)&q0;
        o.y = *(unsigned int*)&q1;
        o.z = *(unsigned int*)&q2;
        o.w = *(unsigned int*)&q3;
        ((uint4*)h0)[i] = o;
    }

    // ---------- Phase A2: bucket sort into fixed-cap regions ----------
    const int nTiles = (E + T_TILE - 1) / T_TILE;
    for (int t = blockIdx.x; t < nTiles; t += G) {
        const int t0 = t * T_TILE;
        sA[tid] = 0;
        __syncthreads();
        for (int i = 0; i < T_TILE / 512; ++i) {
            int idx = t0 + i * 512 + tid;
            if (idx < E) atomicAdd(&sA[L_row[idx] >> NB_SH], 1);
        }
        __syncthreads();
        int x = sA[tid];
        __syncthreads();
        scan512(sA, tid);
        int excl = sA[tid] - x;
        sB[tid] = excl;
        sC[tid] = excl;
        sD[tid] = (x > 0) ? (tid * BCAP + atomicAdd(&bcnt[tid], x)) : 0;
        __syncthreads();
        for (int i = 0; i < T_TILE / 512; ++i) {
            int idx = t0 + i * 512 + tid;
            if (idx < E) {
                int   r = L_row[idx];
                int   c = L_col[idx];
                float v = L_val[idx];
                int   b = r >> NB_SH;
                int   p = atomicAdd(&sC[b], 1);
                unsigned lo = (unsigned)(((r & ((1 << NB_SH) - 1)) << 18) | c);
                sh_data[p] = ((long long)__float_as_int(v) << 32) | (long long)lo;
                sh_gpos[p] = sD[b] + (p - sB[b]);
            }
        }
        __syncthreads();
        int tot = sA[511];
        for (int p = tid; p < tot; p += 512) {
            bedges[sh_gpos[p]] = sh_data[p];
        }
        __syncthreads();
    }

    grid.sync();

    // ---------- Phase B: per-bucket row hist + scan -> rs + placement ----------
    for (int b = blockIdx.x; b < NBUCK; b += G) {
        // global base = prefix over bcnt[0..b)
        sA[tid] = (tid < NBUCK) ? bcnt[tid] : 0;
        __syncthreads();
        scan512(sA, tid);
        int gbase = (b > 0) ? sA[b - 1] : 0;
        const int cnt = bcnt[b];
        const long long* seg = bedges + (size_t)b * BCAP;
        sC[tid] = 0;
        __syncthreads();
        for (int k = tid; k < cnt; k += 512) {
            unsigned lo = (unsigned)seg[k];
            atomicAdd(&sC[lo >> 18], 1);
        }
        __syncthreads();
        int x = sC[tid];
        sB[tid] = x;
        __syncthreads();
        scan512(sB, tid);
        int excl = sB[tid] - x;
        int rrow = (b << NB_SH) + tid;
        if (rrow < N) rs[rrow] = gbase + excl;
        if (b == NBUCK - 1 && tid == 0) rs[N] = E;
        sC[tid] = excl;
        __syncthreads();
        for (int k = tid; k < cnt; k += 512) {
            long long be = seg[k];
            unsigned lo = (unsigned)be;
            int p = atomicAdd(&sC[lo >> 18], 1);
            edges[gbase + p] = make_int2((int)(lo & 0x3FFFF), (int)(be >> 32));
        }
        __syncthreads();
    }

    grid.sync();

    // ---------- Phase C: two full SpMMs ----------
    spmm_phase(rs, edges, h0, h1, N);
    grid.sync();
    spmm_phase(rs, edges, h1, h2, N);
    grid.sync();

    // ---------- Phase D: fused pair (emb + h1 + h2 + L.h2 at sampled rows, dot) ----
    {
        const int wid    = (blockIdx.x << 3) + (tid >> 6);
        const int lane   = tid & 63;
        const int half   = lane >> 5;
        const int l32    = lane & 31;
        const int stride = G << 3;
        for (int w = wid; w < B; w += stride) {
            int row;
            const float* emb;
            if (half == 0) {
                int u = uIdx[w];
                row = u;
                emb = uE + (size_t)u * EMBED;
            } else {
                int it = vIdx[w];
                row = userNum + it;
                emb = iE + (size_t)it * EMBED;
            }
            float4 acc = *(const float4*)(emb + 4 * l32);
            size_t ro = (size_t)row * EMBED + 4 * l32;
            uint2 r1 = *(const uint2*)(h1 + ro);
            uint2 r2 = *(const uint2*)(h2 + ro);
            {
                __half2 a0 = *(__half2*)&r1.x, a1 = *(__half2*)&r1.y;
                __half2 b0 = *(__half2*)&r2.x, b1 = *(__half2*)&r2.y;
                acc.x += __half2float(a0.x) + __half2float(b0.x);
                acc.y += __half2float(a0.y) + __half2float(b0.y);
                acc.z += __half2float(a1.x) + __half2float(b1.x);
                acc.w += __half2float(a1.y) + __half2float(b1.y);
            }
            int s = rs[row], e = rs[row + 1];
            for (int k = s; k < e; k += CHUNK) {
                uint2 raw[CHUNK];
                float vv[CHUNK];
                #pragma unroll
                for (int j = 0; j < CHUNK; ++j) {
                    bool ok  = (k + j) < e;
                    int  idx = ok ? (k + j) : s;
                    int2 ed  = edges[idx];
                    vv[j]    = ok ? __int_as_float(ed.y) : 0.f;
                    raw[j]   = *(const uint2*)(h2 + (size_t)ed.x * EMBED + 4 * l32);
                }
                #pragma unroll
                for (int j = 0; j < CHUNK; ++j) {
                    __half2 h01 = *(__half2*)&raw[j].x;
                    __half2 h23 = *(__half2*)&raw[j].y;
                    acc.x = fmaf(__half2float(h01.x), vv[j], acc.x);
                    acc.y = fmaf(__half2float(h01.y), vv[j], acc.y);
                    acc.z = fmaf(__half2float(h23.x), vv[j], acc.z);
                    acc.w = fmaf(__half2float(h23.y), vv[j], acc.w);
                }
            }
            float ox = __shfl_xor(acc.x, 32);
            float oy = __shfl_xor(acc.y, 32);
            float oz = __shfl_xor(acc.z, 32);
            float ow = __shfl_xor(acc.w, 32);
            float sdot = acc.x * ox + acc.y * oy + acc.z * oz + acc.w * ow;
            #pragma unroll
            for (int off = 16; off > 0; off >>= 1) sdot += __shfl_down(sdot, off, 32);
            sdot += __shfl_down(sdot, 32);
            if (lane == 0) out[w] = sdot * (1.f / 32.f);
        }
    }
}

// ---------------- launch ----------------

extern "C" void kernel_launch(void* const* d_in, const int* in_sizes, int n_in,
                              void* d_out, int out_size, void* d_ws, size_t ws_size,
                              hipStream_t stream) {
    const float* uE      = (const float*)d_in[0];
    const float* iE      = (const float*)d_in[1];
    const float* L_val   = (const float*)d_in[2];
    const int*   L_row   = (const int*)d_in[3];
    const int*   L_col   = (const int*)d_in[4];
    const int*   userIdx = (const int*)d_in[5];
    const int*   itemIdx = (const int*)d_in[6];

    int userNum = in_sizes[0] / EMBED;   // 100000
    int itemNum = in_sizes[1] / EMBED;   // 50000
    int N = userNum + itemNum;           // 150000
    int E = in_sizes[2];                 // 2000000
    int B = in_sizes[5];                 // 16384
    float* out = (float*)d_out;

    char* ws = (char*)d_ws;
    size_t off = 0;
    auto alloc = [&](size_t bytes) -> void* {
        void* p = ws + off;
        off += (bytes + 1023) & ~(size_t)1023;
        return p;
    };
    const int NBUCK = (N + (1 << NB_SH) - 1) >> NB_SH;   // 293
    __half* h0     = (__half*)alloc((size_t)N * EMBED * 2);
    __half* h1     = (__half*)alloc((size_t)N * EMBED * 2);
    __half* h2     = (__half*)alloc((size_t)N * EMBED * 2);
    int2*   edges  = (int2*) alloc((size_t)E * 8);
    long long* bedges = (long long*)alloc((size_t)NBUCK * BCAP * 8);
    int*    rs     = (int*)  alloc((size_t)(N + 1) * 4);
    int*    bcnt   = (int*)  alloc(2048);
    (void)off; (void)ws_size; (void)n_in; (void)out_size;

    (void)hipMemsetAsync(bcnt, 0, 2048, stream);

    int nu8   = userNum * EMBED / 8;
    int ntot8 = N * EMBED / 8;

    int nb = 0;
    if (hipOccupancyMaxActiveBlocksPerMultiprocessor(&nb, mega, 512, 0) != hipSuccess
        || nb < 1) nb = 2;
    if (nb > 4) nb = 4;                  // 2048 threads/CU cap
    int grid = nb * 256;

    void* args[] = {
        (void*)&uE, (void*)&iE, (void*)&L_row, (void*)&L_col, (void*)&L_val,
        (void*)&userIdx, (void*)&itemIdx, (void*)&out,
        (void*)&h0, (void*)&h1, (void*)&h2,
        (void*)&edges, (void*)&bedges, (void*)&rs, (void*)&bcnt,
        (void*)&N, (void*)&E, (void*)&B, (void*)&userNum,
        (void*)&nu8, (void*)&ntot8
    };
    (void)hipLaunchCooperativeKernel(mega, dim3(grid), dim3(512), args, 0, stream);
}